// Round 7
// baseline (867.732 us; speedup 1.0000x reference)
//
#include <hip/hip_runtime.h>
#include <math.h>

typedef short bf16x8 __attribute__((ext_vector_type(8)));
typedef float f32x4  __attribute__((ext_vector_type(4)));

__device__ __forceinline__ float phi_act(float t) {
    return t / (1.0f + __expf(-t)) + 1.0f;   // silu(t)+1
}

__device__ __forceinline__ unsigned short f2bf(float f) {
    union { float f; unsigned int u; } un; un.f = f;
    unsigned int r = un.u + 0x7fffu + ((un.u >> 16) & 1u);  // RNE
    return (unsigned short)(r >> 16);
}

__device__ __forceinline__ void gload_lds16(const void* g, void* l) {
    __builtin_amdgcn_global_load_lds(
        (const __attribute__((address_space(1))) void*)g,
        (__attribute__((address_space(3))) void*)l, 16, 0, 0);
}

// ============================================================================
// GEMM body: R3/R5 verified structure (qkv 236us, MfmaUtil 38%) -- FROZEN.
// 24 ds_read_b128 per wave per K-tile, 3 gated phases + 1 free phase,
// counted vmcnt FIFO (see R5 ledger), LDS XOR-swizzle via inverse-swizzled
// global source. KIND==1 selects per-batch B (Weff_b).
// ============================================================================

__device__ __forceinline__ void stage2(const char* g, int voff0, int voff1,
                                       char* l, int wb16) {
    gload_lds16(g + voff0, l + wb16);
    gload_lds16(g + voff1, l + 8192 + wb16);
}

#define LOAD_AF(buf, ah) do {                                                   \
    const char* _s = (const char*)&As[buf][ah][0];                              \
    _Pragma("unroll")                                                           \
    for (int _mi = 0; _mi < 4; _mi++) {                                         \
        const int _row = qm * 64 + _mi * 16 + ml;                               \
        const int _sw = (_row & 7) << 4;                                        \
        _Pragma("unroll")                                                       \
        for (int _ks = 0; _ks < 2; _ks++)                                       \
            af[_mi][_ks] = *(const bf16x8*)(_s +                                \
                (((_row * 128) + _ks * 64 + kq * 16) ^ _sw));                   \
    }                                                                           \
} while (0)

#define LOAD_BF_TO(dst, buf, bh) do {                                           \
    const char* _s = (const char*)&Bs[buf][bh][0];                              \
    _Pragma("unroll")                                                           \
    for (int _nj = 0; _nj < 2; _nj++) {                                         \
        const int _col = qn * 32 + _nj * 16 + ml;                               \
        const int _sw = (_col & 7) << 4;                                        \
        _Pragma("unroll")                                                       \
        for (int _ks = 0; _ks < 2; _ks++)                                       \
            dst[_nj][_ks] = *(const bf16x8*)(_s +                               \
                (((_col * 128) + _ks * 64 + kq * 16) ^ _sw));                   \
    }                                                                           \
} while (0)

#define MFMA_Q(Q, B) do {                                                       \
    __builtin_amdgcn_s_setprio(1);                                              \
    _Pragma("unroll")                                                           \
    for (int _mi = 0; _mi < 4; _mi++)                                           \
        _Pragma("unroll")                                                       \
        for (int _nj = 0; _nj < 2; _nj++)                                       \
            _Pragma("unroll")                                                   \
            for (int _ks = 0; _ks < 2; _ks++)                                   \
                acc[Q][_mi][_nj] = __builtin_amdgcn_mfma_f32_16x16x32_bf16(     \
                    af[_mi][_ks], B[_nj][_ks], acc[Q][_mi][_nj], 0, 0, 0);      \
    __builtin_amdgcn_s_setprio(0);                                              \
} while (0)

// KIND 0: fused QKV (W = concat[Wq;Wk;Wv], N=3072, per-column-block epilogue)
// KIND 1: out projection, B = per-batch Weff_b (fp32 store + bias, N=1024)
template<int KIND>
__device__ __forceinline__ void gemm256_body(
    const unsigned short* __restrict__ A, const unsigned short* __restrict__ W,
    const float* __restrict__ bq, const float* __restrict__ bv,
    unsigned short* __restrict__ oq, unsigned short* __restrict__ okk,
    unsigned short* __restrict__ ov, float* __restrict__ outF,
    const float* __restrict__ bo, float scale, int NBN)
{
    __shared__ __align__(128) unsigned short As[2][2][128 * 64];
    __shared__ __align__(128) unsigned short Bs[2][2][128 * 64];

    const int tid  = threadIdx.x;
    const int lane = tid & 63;
    const int w    = tid >> 6;
    const int qm   = w >> 2;         // 0..1 : 64-row band within quadrant
    const int qn   = w & 3;          // 0..3 : 32-col band within quadrant
    const int ml   = lane & 15;
    const int kq   = lane >> 4;

    // T1: bijective XCD swizzle (nwg % 8 == 0), bm-major chunks
    const int nwg  = (int)gridDim.x;
    const int bid  = (int)blockIdx.x;
    const int sbid = (bid & 7) * (nwg >> 3) + (bid >> 3);
    const int bn   = sbid % NBN;
    const int bm   = sbid / NBN;

    const char* pA = (const char*)(A + (size_t)bm * 256 * 1024);
    const unsigned short* Wbase =
        (KIND == 1) ? (W + (size_t)(bm >> 4) * 1024 * 1024) : W;
    const char* pB = (const char*)(Wbase + (size_t)bn * 256 * 1024);

    // per-lane staging offsets (inverse-swizzled global source), computed once
    int voff[2];
    #pragma unroll
    for (int u = 0; u < 2; u++) {
        const int p  = (u * 512 + tid) * 16;
        const int qq = p ^ (((p >> 7) & 7) << 4);
        voff[u] = (qq >> 7) * 2048 + (qq & 127);
    }
    const int wb16 = (tid & ~63) * 16;

    f32x4 acc[4][4][2];
    f32x4 zero4 = {0.f, 0.f, 0.f, 0.f};
    #pragma unroll
    for (int q = 0; q < 4; q++)
        #pragma unroll
        for (int mi = 0; mi < 4; mi++)
            #pragma unroll
            for (int nj = 0; nj < 2; nj++) acc[q][mi][nj] = zero4;

    bf16x8 af[4][2], bf0[2][2], bf1[2][2];

    // Prologue: stage tile0 in steady-state FIFO order [a0, b0, b1, a1]
    stage2(pA,              voff[0], voff[1], (char*)&As[0][0][0], wb16);
    stage2(pB,              voff[0], voff[1], (char*)&Bs[0][0][0], wb16);
    stage2(pB + 256 * 1024, voff[0], voff[1], (char*)&Bs[0][1][0], wb16);
    stage2(pA + 256 * 1024, voff[0], voff[1], (char*)&As[0][1][0], wb16);

    for (int t = 0; t < 16; ++t) {
        const int buf = t & 1;
        const char* A0n = pA + (size_t)(t + 1) * 128;            // next K-tile
        const char* A1n = A0n + 256 * 1024;
        const char* B0n = pB + (size_t)(t + 1) * 128;
        const char* B1n = B0n + 256 * 1024;
        const bool st = (t + 1 < 16);

        // ---------------- P0 : Q0 = af0 x bf0 ----------------
        asm volatile("s_waitcnt vmcnt(4)" ::: "memory");
        __builtin_amdgcn_s_barrier();
        asm volatile("" ::: "memory");
        LOAD_AF(buf, 0);
        LOAD_BF_TO(bf0, buf, 0);
        if (st) {
            stage2(A0n, voff[0], voff[1], (char*)&As[buf ^ 1][0][0], wb16);
            stage2(B0n, voff[0], voff[1], (char*)&Bs[buf ^ 1][0][0], wb16);
        }
        asm volatile("s_waitcnt lgkmcnt(0)" ::: "memory");
        MFMA_Q(0, bf0);

        // ---------------- P1 : Q1 = af0 x bf1 ----------------
        if (st) { asm volatile("s_waitcnt vmcnt(6)" ::: "memory"); }
        else    { asm volatile("s_waitcnt vmcnt(2)" ::: "memory"); }
        __builtin_amdgcn_s_barrier();
        asm volatile("" ::: "memory");
        LOAD_BF_TO(bf1, buf, 1);
        if (st) stage2(B1n, voff[0], voff[1], (char*)&Bs[buf ^ 1][1][0], wb16);
        asm volatile("s_waitcnt lgkmcnt(0)" ::: "memory");
        MFMA_Q(1, bf1);

        // ---------------- P2 : Q2 = af1 x bf1 ----------------
        if (st) { asm volatile("s_waitcnt vmcnt(6)" ::: "memory"); }
        else    { asm volatile("s_waitcnt vmcnt(0)" ::: "memory"); }
        __builtin_amdgcn_s_barrier();
        asm volatile("" ::: "memory");
        LOAD_AF(buf, 1);
        if (st) stage2(A1n, voff[0], voff[1], (char*)&As[buf ^ 1][1][0], wb16);
        asm volatile("s_waitcnt lgkmcnt(0)" ::: "memory");
        MFMA_Q(2, bf1);

        // ---------------- P3 : Q3 = af1 x bf0 (no sync) ----------------
        MFMA_Q(3, bf0);
    }

    // Epilogue
    const int rq = lane >> 4, cl = lane & 15;
    #pragma unroll
    for (int q = 0; q < 4; q++) {
        const int qr = (q >> 1) * 128;
        const int qc = ((q == 1) || (q == 2)) ? 128 : 0;
        #pragma unroll
        for (int nj = 0; nj < 2; nj++) {
            const int colg = bn * 256 + qc + qn * 32 + nj * 16 + cl;
            if constexpr (KIND == 0) {
                const int z    = colg >> 10;        // uniform across the 16 lanes
                const int lcol = colg & 1023;
                const float bias = (z == 0) ? bq[lcol] : ((z == 2) ? bv[lcol] : 0.f);
                unsigned short* dst = (z == 0) ? oq : ((z == 1) ? okk : ov);
                #pragma unroll
                for (int mi = 0; mi < 4; mi++) {
                    const int row0 = bm * 256 + qr + qm * 64 + mi * 16 + rq * 4;
                    #pragma unroll
                    for (int r = 0; r < 4; r++) {
                        float vv = acc[q][mi][nj][r] + bias;
                        if (z < 2) vv = phi_act(vv * scale);
                        dst[(size_t)(row0 + r) * 1024 + lcol] = f2bf(vv);
                    }
                }
            } else {
                const float bias = bo[colg];
                #pragma unroll
                for (int mi = 0; mi < 4; mi++) {
                    const int row0 = bm * 256 + qr + qm * 64 + mi * 16 + rq * 4;
                    #pragma unroll
                    for (int r = 0; r < 4; r++)
                        outF[(size_t)(row0 + r) * 1024 + colg] = acc[q][mi][nj][r] + bias;
                }
            }
        }
    }
}

__global__ __launch_bounds__(512, 2) void qkv_gemm256(
    const unsigned short* __restrict__ xb,
    const unsigned short* __restrict__ wcat,   // wq,wk,wv contiguous [3072][1024]
    const float* __restrict__ bq, const float* __restrict__ bv,
    unsigned short* __restrict__ phiq, unsigned short* __restrict__ phik,
    unsigned short* __restrict__ vb, float scale)
{
    gemm256_body<0>(xb, wcat, bq, bv, phiq, phik, vb, nullptr, nullptr, scale, 12);
}

__global__ __launch_bounds__(512, 2) void out_gemm256(
    const unsigned short* __restrict__ A, const unsigned short* __restrict__ W,
    const float* __restrict__ bo, float* __restrict__ out)
{
    gemm256_body<1>(A, W, nullptr, nullptr, nullptr, nullptr, nullptr, out, bo, 1.0f, 4);
}

// ---------------- cast (x + Wq,Wk,Wv only; Wo consumed fp32 in kv_fused) ----
__global__ __launch_bounds__(256) void cast_all(
    const float* __restrict__ x,  unsigned short* __restrict__ xb,
    const float* __restrict__ w0, unsigned short* __restrict__ w0b,
    const float* __restrict__ w1, unsigned short* __restrict__ w1b,
    const float* __restrict__ w2, unsigned short* __restrict__ w2b,
    size_t nx, size_t nw)
{
    size_t i = ((size_t)blockIdx.x * 256 + threadIdx.x) * 4;
    const float* s; unsigned short* d; size_t off;
    if (i < nx)               { s = x;  d = xb;  off = i; }
    else if (i < nx + nw)     { s = w0; d = w0b; off = i - nx; }
    else if (i < nx + 2 * nw) { s = w1; d = w1b; off = i - nx - nw; }
    else                      { s = w2; d = w2b; off = i - nx - 2 * nw; }
    float4 v = *(const float4*)(s + off);
    ushort4 o;
    o.x = f2bf(v.x); o.y = f2bf(v.y); o.z = f2bf(v.z); o.w = f2bf(v.w);
    *(ushort4*)(d + off) = o;
}

// ---------------- fused kv: partials + last-block reduce + Weff ----------------
// R7: single launch replaces kv_part + kv_weff. Grid (8 tc, 128 bh), 256 thr.
// Phase 1 (all blocks): MFMA split-T partial of kv_h = phi_k^T v over 512 t,
// written to partial[(bh*8+tc)]. Then __threadfence (release) + atomicAdd on
// cnt[bh]; the block seeing old==7 is the FINISHER for (b,h):
// Phase 2 (finisher only): acquire fence; reduce 8 partials -> kv[d][e] bf16
// in LDS; Weff_b[o][h*64+d] = sum_e Wo[o][h*64+e]*kv[d][e] with Wo fragments
// loaded DIRECTLY from fp32 global (no wob cast, no LDS staging, no vmcnt(0)
// serial stages). Deadlock-free: non-finishers never wait.
// cnt[] zeroed by a 512B hipMemsetAsync in the same stream each replay.
__global__ __launch_bounds__(256) void kv_fused(
    const unsigned short* __restrict__ phiK, const unsigned short* __restrict__ V,
    const float* __restrict__ Wo, float* __restrict__ partial,
    unsigned int* __restrict__ cnt, unsigned short* __restrict__ weff,
    int Ttot, int D)
{
    const int tc = blockIdx.x, bh = blockIdx.y;
    const int b = bh >> 4, h = bh & 15;
    const int tbase = tc * 512;

    __shared__ unsigned short pkT[64][72];   // [d][t-swizzled], +8 pad
    __shared__ unsigned short vvT[64][72];   // [e][t-swizzled]
    __shared__ unsigned short kvs[64][72];   // finisher: kv[d][e], +8 pad
    __shared__ unsigned int is_last;

    const int tid  = threadIdx.x;
    const int lane = tid & 63;
    const int w    = tid >> 6;
    const int dq = w >> 1, eq = w & 1;
    const int kq = lane >> 4, ml = lane & 15;

    const int tq  = tid >> 3;            // 0..31 (t-pair index)
    const int oct = tid & 7;             // d-octet
    const int d8  = oct * 8;
    const int tw0 = (tq * 2) ^ (oct << 3);  // swizzled column (even)

    f32x4 zero4 = {0.f, 0.f, 0.f, 0.f};
    f32x4 acc[2][2];
    acc[0][0] = zero4; acc[0][1] = zero4; acc[1][0] = zero4; acc[1][1] = zero4;

    const size_t base = (size_t)b * Ttot * D + h * 64;

#define PACKW(arr, lo, hi, i0)                                                   \
    *(unsigned int*)&arr[d8 + i0    ][tw0] = ((lo) & 0xffffu) | ((hi) << 16);    \
    *(unsigned int*)&arr[d8 + i0 + 1][tw0] = ((lo) >> 16) | ((hi) & 0xffff0000u);

    for (int c8 = 0; c8 < 8; c8++) {
        const int t0 = tbase + c8 * 64;
        __syncthreads();
        {
            const size_t g0 = base + (size_t)(t0 + tq * 2) * D + d8;
            uint4 k0 = *(const uint4*)(phiK + g0);
            uint4 k1 = *(const uint4*)(phiK + g0 + D);
            uint4 v0 = *(const uint4*)(V + g0);
            uint4 v1 = *(const uint4*)(V + g0 + D);
            PACKW(pkT, k0.x, k1.x, 0) PACKW(pkT, k0.y, k1.y, 2)
            PACKW(pkT, k0.z, k1.z, 4) PACKW(pkT, k0.w, k1.w, 6)
            PACKW(vvT, v0.x, v1.x, 0) PACKW(vvT, v0.y, v1.y, 2)
            PACKW(vvT, v0.z, v1.z, 4) PACKW(vvT, v0.w, v1.w, 6)
        }
        __syncthreads();

        #pragma unroll
        for (int ks = 0; ks < 2; ks++) {
            bf16x8 afr[2], bfv[2];
            #pragma unroll
            for (int ai = 0; ai < 2; ai++) {
                const int row = dq * 32 + ai * 16 + ml;
                const int col = ((ks * 4 + kq) ^ ((row >> 3) & 7)) << 3;
                afr[ai] = *(const bf16x8*)&pkT[row][col];
            }
            #pragma unroll
            for (int bi = 0; bi < 2; bi++) {
                const int row = eq * 32 + bi * 16 + ml;
                const int col = ((ks * 4 + kq) ^ ((row >> 3) & 7)) << 3;
                bfv[bi] = *(const bf16x8*)&vvT[row][col];
            }
            #pragma unroll
            for (int ai = 0; ai < 2; ai++)
                #pragma unroll
                for (int bi = 0; bi < 2; bi++)
                    acc[ai][bi] = __builtin_amdgcn_mfma_f32_16x16x32_bf16(
                        afr[ai], bfv[bi], acc[ai][bi], 0, 0, 0);
        }
    }
#undef PACKW

    {
        float* outp = partial + ((size_t)bh * 8 + tc) * 4096;
        const int rq = lane >> 4, cl = lane & 15;
        #pragma unroll
        for (int ai = 0; ai < 2; ai++)
            #pragma unroll
            for (int bi = 0; bi < 2; bi++) {
                const int e = eq * 32 + bi * 16 + cl;
                #pragma unroll
                for (int r = 0; r < 4; r++) {
                    const int d = dq * 32 + ai * 16 + rq * 4 + r;
                    outp[d * 64 + e] = acc[ai][bi][r];
                }
            }
    }

    // -------- last-block election --------
    __threadfence();                         // release partial writes
    if (tid == 0) {
        unsigned int old = atomicAdd(&cnt[bh], 1u);
        is_last = (old == 7u) ? 1u : 0u;
    }
    __syncthreads();
    if (!is_last) return;
    __threadfence();                         // acquire all 8 partials

    // -------- finisher: reduce -> kvs (bf16) --------
    {
        float a[16];
        #pragma unroll
        for (int c = 0; c < 16; c++) a[c] = 0.f;
        #pragma unroll
        for (int p = 0; p < 8; p++) {
            const float* src = partial + ((size_t)bh * 8 + p) * 4096;
            #pragma unroll
            for (int c = 0; c < 16; c++) a[c] += src[c * 256 + tid];
        }
        #pragma unroll
        for (int c = 0; c < 16; c++) {
            const int idx = c * 256 + tid;       // d*64+e
            kvs[idx >> 6][idx & 63] = f2bf(a[c]);
        }
    }
    __syncthreads();

    // B fragments: B[n=d][k=e]
    bf16x8 bkv[4][2];
    #pragma unroll
    for (int nj = 0; nj < 4; nj++)
        #pragma unroll
        for (int ks = 0; ks < 2; ks++)
            bkv[nj][ks] = *(const bf16x8*)&kvs[nj * 16 + ml][ks * 32 + kq * 8];

    unsigned short* dstb = weff + (size_t)b * 1024 * 1024 + h * 64;
    const float* wsl = Wo + (size_t)h * 64;  // Wo[o][h*64+..], row stride 1024
    const int rq = lane >> 4, cl = lane & 15;

    for (int oc = 0; oc < 8; ++oc) {
        // A fragments direct from fp32 global: A[m=o][k=e]
        bf16x8 awo[2][2];
        #pragma unroll
        for (int mi = 0; mi < 2; mi++) {
            const int o = oc * 128 + w * 32 + mi * 16 + ml;
            #pragma unroll
            for (int ks = 0; ks < 2; ks++) {
                const float* p = wsl + (size_t)o * 1024 + ks * 32 + kq * 8;
                float4 f0 = *(const float4*)p;
                float4 f1 = *(const float4*)(p + 4);
                bf16x8 a;
                a[0] = (short)f2bf(f0.x); a[1] = (short)f2bf(f0.y);
                a[2] = (short)f2bf(f0.z); a[3] = (short)f2bf(f0.w);
                a[4] = (short)f2bf(f1.x); a[5] = (short)f2bf(f1.y);
                a[6] = (short)f2bf(f1.z); a[7] = (short)f2bf(f1.w);
                awo[mi][ks] = a;
            }
        }

        f32x4 acc2[2][4];
        #pragma unroll
        for (int mi = 0; mi < 2; mi++)
            #pragma unroll
            for (int nj = 0; nj < 4; nj++) acc2[mi][nj] = zero4;

        #pragma unroll
        for (int ks = 0; ks < 2; ks++)
            #pragma unroll
            for (int mi = 0; mi < 2; mi++)
                #pragma unroll
                for (int nj = 0; nj < 4; nj++)
                    acc2[mi][nj] = __builtin_amdgcn_mfma_f32_16x16x32_bf16(
                        awo[mi][ks], bkv[nj][ks], acc2[mi][nj], 0, 0, 0);

        #pragma unroll
        for (int mi = 0; mi < 2; mi++)
            #pragma unroll
            for (int nj = 0; nj < 4; nj++)
                #pragma unroll
                for (int r = 0; r < 4; r++) {
                    const int o = oc * 128 + w * 32 + mi * 16 + rq * 4 + r;
                    dstb[(size_t)o * 1024 + nj * 16 + cl] = f2bf(acc2[mi][nj][r]);
                }
    }
}

extern "C" void kernel_launch(void* const* d_in, const int* in_sizes, int n_in,
                              void* d_out, int out_size, void* d_ws, size_t ws_size,
                              hipStream_t stream) {
    const float* x  = (const float*)d_in[0];
    const float* Wq = (const float*)d_in[1];
    const float* bq = (const float*)d_in[2];
    const float* Wk = (const float*)d_in[3];
    const float* Wv = (const float*)d_in[4];
    const float* bv = (const float*)d_in[5];
    const float* Wo = (const float*)d_in[6];
    const float* bo = (const float*)d_in[7];
    float* out = (float*)d_out;

    const int B = 8, T = 4096, D = 1024;
    const int M = B * T;                       // 32768
    const float scale = 0.35355339059327379f;  // 64^-0.25
    const size_t MD = (size_t)M * D;
    const size_t WN = (size_t)D * D;

    unsigned short* xb    = (unsigned short*)d_ws;
    unsigned short* wqb   = xb + MD;           // wq,wk,wv contiguous = [3072][1024]
    unsigned short* wkb   = wqb + WN;
    unsigned short* wvb   = wkb + WN;
    unsigned short* phiq  = wvb + WN;
    unsigned short* phik  = phiq + MD;
    unsigned short* vb    = phik + MD;
    unsigned short* weff  = vb + MD;                    // [8][1024][1024] bf16 = 16 MB
    float*          part  = (float*)(weff + (size_t)8 * 1024 * 1024); // 16 MB
    unsigned int*   cnt   = (unsigned int*)(part + (size_t)1024 * 4096); // 128 u32
    (void)ws_size; (void)in_sizes; (void)n_in; (void)out_size;

    dim3 blk(256);

    // 0) zero finisher counters (tiny, in-graph)
    hipMemsetAsync(cnt, 0, 128 * sizeof(unsigned int), stream);

    // 1) cast x + Wq/Wk/Wv to bf16 (Wo stays fp32, consumed by kv_fused)
    {
        size_t total4 = (MD + 3 * WN) / 4;
        cast_all<<<dim3((unsigned)(total4 / 256)), blk, 0, stream>>>(
            x, xb, Wq, wqb, Wk, wkb, Wv, wvb, MD, WN);
    }

    // 2) fused q/k/v projection: one GEMM M=32768, N=3072, K=1024
    qkv_gemm256<<<dim3(1536), dim3(512), 0, stream>>>(
        xb, wqb, bq, bv, phiq, phik, vb, scale);

    // 3) fused kv partials + last-block reduce + Weff fold
    kv_fused<<<dim3(8, 128), blk, 0, stream>>>(
        phik, vb, Wo, part, cnt, weff, T, D);

    // 4) final projection directly from phiq: out = phiq @ Weff_b^T + bo
    out_gemm256<<<dim3(512), dim3(512), 0, stream>>>(phiq, weff, bo, out);
}

// Round 8
// 593.723 us; speedup vs baseline: 1.4615x; 1.4615x over previous
//
#include <hip/hip_runtime.h>
#include <math.h>

typedef short bf16x8 __attribute__((ext_vector_type(8)));
typedef float f32x4  __attribute__((ext_vector_type(4)));

__device__ __forceinline__ float phi_act(float t) {
    return t / (1.0f + __expf(-t)) + 1.0f;   // silu(t)+1
}

__device__ __forceinline__ unsigned short f2bf(float f) {
    union { float f; unsigned int u; } un; un.f = f;
    unsigned int r = un.u + 0x7fffu + ((un.u >> 16) & 1u);  // RNE
    return (unsigned short)(r >> 16);
}

__device__ __forceinline__ void gload_lds16(const void* g, void* l) {
    __builtin_amdgcn_global_load_lds(
        (const __attribute__((address_space(1))) void*)g,
        (__attribute__((address_space(3))) void*)l, 16, 0, 0);
}

// ============================================================================
// GEMM body: R3/R5 verified structure (qkv 236us, MfmaUtil 38%) -- FROZEN,
// except R8 removes s_setprio around MFMA (m190: neutral-to-negative on
// barrier-lockstep GEMM schedules; only pays on phase-role-split schedules).
// 24 ds_read_b128 per wave per K-tile, 3 gated phases + 1 free phase,
// counted vmcnt FIFO (see ledger below), LDS XOR-swizzle via inverse-swizzled
// global source. KIND==1 selects per-batch B (Weff_b).
// vmcnt FIFO ledger (stage issue order per tile = [a0',b0',b1',a1']):
//   P0 entry: outstanding = [a0,b0,b1,a1](8) -> vmcnt(4) completes a0,b0
//   P1 entry: [b1,a1,a0',b0'](8)            -> vmcnt(6) completes b1
//   P2 entry: [a1,a0',b0',b1'](8)           -> vmcnt(6) completes a1
//   (t=15: no new stages -> gates 4/2/0)
// WAR: stage in phase p targets a slot whose last read drained at that wave's
// lgkm(0) in the same phase of tile t-1 -> safe.
// NOTE (R7 lesson): per-block __threadfence (device scope) costs ~300us at
// 1024 blocks on MI355X (L2 wb/inv storm) -- never fuse via fences here.
// ============================================================================

__device__ __forceinline__ void stage2(const char* g, int voff0, int voff1,
                                       char* l, int wb16) {
    gload_lds16(g + voff0, l + wb16);
    gload_lds16(g + voff1, l + 8192 + wb16);
}

#define LOAD_AF(buf, ah) do {                                                   \
    const char* _s = (const char*)&As[buf][ah][0];                              \
    _Pragma("unroll")                                                           \
    for (int _mi = 0; _mi < 4; _mi++) {                                         \
        const int _row = qm * 64 + _mi * 16 + ml;                               \
        const int _sw = (_row & 7) << 4;                                        \
        _Pragma("unroll")                                                       \
        for (int _ks = 0; _ks < 2; _ks++)                                       \
            af[_mi][_ks] = *(const bf16x8*)(_s +                                \
                (((_row * 128) + _ks * 64 + kq * 16) ^ _sw));                   \
    }                                                                           \
} while (0)

#define LOAD_BF_TO(dst, buf, bh) do {                                           \
    const char* _s = (const char*)&Bs[buf][bh][0];                              \
    _Pragma("unroll")                                                           \
    for (int _nj = 0; _nj < 2; _nj++) {                                         \
        const int _col = qn * 32 + _nj * 16 + ml;                               \
        const int _sw = (_col & 7) << 4;                                        \
        _Pragma("unroll")                                                       \
        for (int _ks = 0; _ks < 2; _ks++)                                       \
            dst[_nj][_ks] = *(const bf16x8*)(_s +                               \
                (((_col * 128) + _ks * 64 + kq * 16) ^ _sw));                   \
    }                                                                           \
} while (0)

#define MFMA_Q(Q, B) do {                                                       \
    _Pragma("unroll")                                                           \
    for (int _mi = 0; _mi < 4; _mi++)                                           \
        _Pragma("unroll")                                                       \
        for (int _nj = 0; _nj < 2; _nj++)                                       \
            _Pragma("unroll")                                                   \
            for (int _ks = 0; _ks < 2; _ks++)                                   \
                acc[Q][_mi][_nj] = __builtin_amdgcn_mfma_f32_16x16x32_bf16(     \
                    af[_mi][_ks], B[_nj][_ks], acc[Q][_mi][_nj], 0, 0, 0);      \
} while (0)

// KIND 0: fused QKV (W = concat[Wq;Wk;Wv], N=3072, per-column-block epilogue)
// KIND 1: out projection, B = per-batch Weff_b (fp32 store + bias, N=1024)
template<int KIND>
__device__ __forceinline__ void gemm256_body(
    const unsigned short* __restrict__ A, const unsigned short* __restrict__ W,
    const float* __restrict__ bq, const float* __restrict__ bv,
    unsigned short* __restrict__ oq, unsigned short* __restrict__ okk,
    unsigned short* __restrict__ ov, float* __restrict__ outF,
    const float* __restrict__ bo, float scale, int NBN)
{
    __shared__ __align__(128) unsigned short As[2][2][128 * 64];
    __shared__ __align__(128) unsigned short Bs[2][2][128 * 64];

    const int tid  = threadIdx.x;
    const int lane = tid & 63;
    const int w    = tid >> 6;
    const int qm   = w >> 2;         // 0..1 : 64-row band within quadrant
    const int qn   = w & 3;          // 0..3 : 32-col band within quadrant
    const int ml   = lane & 15;
    const int kq   = lane >> 4;

    // T1: bijective XCD swizzle (nwg % 8 == 0), bm-major chunks
    const int nwg  = (int)gridDim.x;
    const int bid  = (int)blockIdx.x;
    const int sbid = (bid & 7) * (nwg >> 3) + (bid >> 3);
    const int bn   = sbid % NBN;
    const int bm   = sbid / NBN;

    const char* pA = (const char*)(A + (size_t)bm * 256 * 1024);
    const unsigned short* Wbase =
        (KIND == 1) ? (W + (size_t)(bm >> 4) * 1024 * 1024) : W;
    const char* pB = (const char*)(Wbase + (size_t)bn * 256 * 1024);

    // per-lane staging offsets (inverse-swizzled global source), computed once
    int voff[2];
    #pragma unroll
    for (int u = 0; u < 2; u++) {
        const int p  = (u * 512 + tid) * 16;
        const int qq = p ^ (((p >> 7) & 7) << 4);
        voff[u] = (qq >> 7) * 2048 + (qq & 127);
    }
    const int wb16 = (tid & ~63) * 16;

    f32x4 acc[4][4][2];
    f32x4 zero4 = {0.f, 0.f, 0.f, 0.f};
    #pragma unroll
    for (int q = 0; q < 4; q++)
        #pragma unroll
        for (int mi = 0; mi < 4; mi++)
            #pragma unroll
            for (int nj = 0; nj < 2; nj++) acc[q][mi][nj] = zero4;

    bf16x8 af[4][2], bf0[2][2], bf1[2][2];

    // Prologue: stage tile0 in steady-state FIFO order [a0, b0, b1, a1]
    stage2(pA,              voff[0], voff[1], (char*)&As[0][0][0], wb16);
    stage2(pB,              voff[0], voff[1], (char*)&Bs[0][0][0], wb16);
    stage2(pB + 256 * 1024, voff[0], voff[1], (char*)&Bs[0][1][0], wb16);
    stage2(pA + 256 * 1024, voff[0], voff[1], (char*)&As[0][1][0], wb16);

    for (int t = 0; t < 16; ++t) {
        const int buf = t & 1;
        const char* A0n = pA + (size_t)(t + 1) * 128;            // next K-tile
        const char* A1n = A0n + 256 * 1024;
        const char* B0n = pB + (size_t)(t + 1) * 128;
        const char* B1n = B0n + 256 * 1024;
        const bool st = (t + 1 < 16);

        // ---------------- P0 : Q0 = af0 x bf0 ----------------
        asm volatile("s_waitcnt vmcnt(4)" ::: "memory");
        __builtin_amdgcn_s_barrier();
        asm volatile("" ::: "memory");
        LOAD_AF(buf, 0);
        LOAD_BF_TO(bf0, buf, 0);
        if (st) {
            stage2(A0n, voff[0], voff[1], (char*)&As[buf ^ 1][0][0], wb16);
            stage2(B0n, voff[0], voff[1], (char*)&Bs[buf ^ 1][0][0], wb16);
        }
        asm volatile("s_waitcnt lgkmcnt(0)" ::: "memory");
        MFMA_Q(0, bf0);

        // ---------------- P1 : Q1 = af0 x bf1 ----------------
        if (st) { asm volatile("s_waitcnt vmcnt(6)" ::: "memory"); }
        else    { asm volatile("s_waitcnt vmcnt(2)" ::: "memory"); }
        __builtin_amdgcn_s_barrier();
        asm volatile("" ::: "memory");
        LOAD_BF_TO(bf1, buf, 1);
        if (st) stage2(B1n, voff[0], voff[1], (char*)&Bs[buf ^ 1][1][0], wb16);
        asm volatile("s_waitcnt lgkmcnt(0)" ::: "memory");
        MFMA_Q(1, bf1);

        // ---------------- P2 : Q2 = af1 x bf1 ----------------
        if (st) { asm volatile("s_waitcnt vmcnt(6)" ::: "memory"); }
        else    { asm volatile("s_waitcnt vmcnt(0)" ::: "memory"); }
        __builtin_amdgcn_s_barrier();
        asm volatile("" ::: "memory");
        LOAD_AF(buf, 1);
        if (st) stage2(A1n, voff[0], voff[1], (char*)&As[buf ^ 1][1][0], wb16);
        asm volatile("s_waitcnt lgkmcnt(0)" ::: "memory");
        MFMA_Q(2, bf1);

        // ---------------- P3 : Q3 = af1 x bf0 (no sync) ----------------
        MFMA_Q(3, bf0);
    }

    // Epilogue
    const int rq = lane >> 4, cl = lane & 15;
    #pragma unroll
    for (int q = 0; q < 4; q++) {
        const int qr = (q >> 1) * 128;
        const int qc = ((q == 1) || (q == 2)) ? 128 : 0;
        #pragma unroll
        for (int nj = 0; nj < 2; nj++) {
            const int colg = bn * 256 + qc + qn * 32 + nj * 16 + cl;
            if constexpr (KIND == 0) {
                const int z    = colg >> 10;        // uniform across the 16 lanes
                const int lcol = colg & 1023;
                const float bias = (z == 0) ? bq[lcol] : ((z == 2) ? bv[lcol] : 0.f);
                unsigned short* dst = (z == 0) ? oq : ((z == 1) ? okk : ov);
                #pragma unroll
                for (int mi = 0; mi < 4; mi++) {
                    const int row0 = bm * 256 + qr + qm * 64 + mi * 16 + rq * 4;
                    #pragma unroll
                    for (int r = 0; r < 4; r++) {
                        float vv = acc[q][mi][nj][r] + bias;
                        if (z < 2) vv = phi_act(vv * scale);
                        dst[(size_t)(row0 + r) * 1024 + lcol] = f2bf(vv);
                    }
                }
            } else {
                const float bias = bo[colg];
                #pragma unroll
                for (int mi = 0; mi < 4; mi++) {
                    const int row0 = bm * 256 + qr + qm * 64 + mi * 16 + rq * 4;
                    #pragma unroll
                    for (int r = 0; r < 4; r++)
                        outF[(size_t)(row0 + r) * 1024 + colg] = acc[q][mi][nj][r] + bias;
                }
            }
        }
    }
}

__global__ __launch_bounds__(512, 2) void qkv_gemm256(
    const unsigned short* __restrict__ xb,
    const unsigned short* __restrict__ wcat,   // wq,wk,wv contiguous [3072][1024]
    const float* __restrict__ bq, const float* __restrict__ bv,
    unsigned short* __restrict__ phiq, unsigned short* __restrict__ phik,
    unsigned short* __restrict__ vb, float scale)
{
    gemm256_body<0>(xb, wcat, bq, bv, phiq, phik, vb, nullptr, nullptr, scale, 12);
}

__global__ __launch_bounds__(512, 2) void out_gemm256(
    const unsigned short* __restrict__ A, const unsigned short* __restrict__ W,
    const float* __restrict__ bo, float* __restrict__ out)
{
    gemm256_body<1>(A, W, nullptr, nullptr, nullptr, nullptr, nullptr, out, bo, 1.0f, 4);
}

// ---------------- cast (grid-stride, 2048 blocks) ----------------
__global__ __launch_bounds__(256) void cast_all(
    const float* __restrict__ x,  unsigned short* __restrict__ xb,
    const float* __restrict__ w0, unsigned short* __restrict__ w0b,
    const float* __restrict__ w1, unsigned short* __restrict__ w1b,
    const float* __restrict__ w2, unsigned short* __restrict__ w2b,
    const float* __restrict__ w3, unsigned short* __restrict__ w3b,
    size_t nx, size_t nw)
{
    const size_t total  = nx + 4 * nw;
    const size_t stride = (size_t)gridDim.x * 256 * 4;
    for (size_t i = ((size_t)blockIdx.x * 256 + threadIdx.x) * 4;
         i < total; i += stride) {
        const float* s; unsigned short* d; size_t off;
        if (i < nx)               { s = x;  d = xb;  off = i; }
        else if (i < nx + nw)     { s = w0; d = w0b; off = i - nx; }
        else if (i < nx + 2 * nw) { s = w1; d = w1b; off = i - nx - nw; }
        else if (i < nx + 3 * nw) { s = w2; d = w2b; off = i - nx - 2 * nw; }
        else                      { s = w3; d = w3b; off = i - nx - 3 * nw; }
        float4 v = *(const float4*)(s + off);
        ushort4 o;
        o.x = f2bf(v.x); o.y = f2bf(v.y); o.z = f2bf(v.z); o.w = f2bf(v.w);
        *(ushort4*)(d + off) = o;
    }
}

// ---------------- kv = phi_k^T v : MFMA split-T partials ----------------
// Packed ds_write_b32 transpose (2 t-rows/thread), t-octet XOR swizzle:
// stored col for (d,t) is t ^ ((d>>3)<<3). Bank audit: 2 lanes/bank = free.
__global__ __launch_bounds__(256) void kv_part(
    const unsigned short* __restrict__ phiK, const unsigned short* __restrict__ V,
    float* __restrict__ partial, int Ttot, int D)
{
    const int tc = blockIdx.x, bh = blockIdx.y;
    const int b = bh >> 4, h = bh & 15;
    const int tbase = tc * 512;

    __shared__ unsigned short pkT[64][72];   // [d][t-swizzled], +8 pad
    __shared__ unsigned short vvT[64][72];   // [e][t-swizzled]

    const int tid  = threadIdx.x;
    const int lane = tid & 63;
    const int w    = tid >> 6;
    const int dq = w >> 1, eq = w & 1;
    const int kq = lane >> 4, ml = lane & 15;

    const int tq  = tid >> 3;            // 0..31 (t-pair index)
    const int oct = tid & 7;             // d-octet
    const int d8  = oct * 8;
    const int tw0 = (tq * 2) ^ (oct << 3);  // swizzled column (even)

    f32x4 zero4 = {0.f, 0.f, 0.f, 0.f};
    f32x4 acc[2][2];
    acc[0][0] = zero4; acc[0][1] = zero4; acc[1][0] = zero4; acc[1][1] = zero4;

    const size_t base = (size_t)b * Ttot * D + h * 64;

#define PACKW(arr, lo, hi, i0)                                                   \
    *(unsigned int*)&arr[d8 + i0    ][tw0] = ((lo) & 0xffffu) | ((hi) << 16);    \
    *(unsigned int*)&arr[d8 + i0 + 1][tw0] = ((lo) >> 16) | ((hi) & 0xffff0000u);

    for (int c8 = 0; c8 < 8; c8++) {
        const int t0 = tbase + c8 * 64;
        __syncthreads();
        {
            const size_t g0 = base + (size_t)(t0 + tq * 2) * D + d8;
            uint4 k0 = *(const uint4*)(phiK + g0);
            uint4 k1 = *(const uint4*)(phiK + g0 + D);
            uint4 v0 = *(const uint4*)(V + g0);
            uint4 v1 = *(const uint4*)(V + g0 + D);
            PACKW(pkT, k0.x, k1.x, 0) PACKW(pkT, k0.y, k1.y, 2)
            PACKW(pkT, k0.z, k1.z, 4) PACKW(pkT, k0.w, k1.w, 6)
            PACKW(vvT, v0.x, v1.x, 0) PACKW(vvT, v0.y, v1.y, 2)
            PACKW(vvT, v0.z, v1.z, 4) PACKW(vvT, v0.w, v1.w, 6)
        }
        __syncthreads();

        #pragma unroll
        for (int ks = 0; ks < 2; ks++) {
            bf16x8 afr[2], bfv[2];
            #pragma unroll
            for (int ai = 0; ai < 2; ai++) {
                const int row = dq * 32 + ai * 16 + ml;
                const int col = ((ks * 4 + kq) ^ ((row >> 3) & 7)) << 3;
                afr[ai] = *(const bf16x8*)&pkT[row][col];
            }
            #pragma unroll
            for (int bi = 0; bi < 2; bi++) {
                const int row = eq * 32 + bi * 16 + ml;
                const int col = ((ks * 4 + kq) ^ ((row >> 3) & 7)) << 3;
                bfv[bi] = *(const bf16x8*)&vvT[row][col];
            }
            #pragma unroll
            for (int ai = 0; ai < 2; ai++)
                #pragma unroll
                for (int bi = 0; bi < 2; bi++)
                    acc[ai][bi] = __builtin_amdgcn_mfma_f32_16x16x32_bf16(
                        afr[ai], bfv[bi], acc[ai][bi], 0, 0, 0);
        }
    }
#undef PACKW

    float* outp = partial + ((size_t)bh * 8 + tc) * 4096;
    const int rq = lane >> 4, cl = lane & 15;
    #pragma unroll
    for (int ai = 0; ai < 2; ai++)
        #pragma unroll
        for (int bi = 0; bi < 2; bi++) {
            const int e = eq * 32 + bi * 16 + cl;
            #pragma unroll
            for (int r = 0; r < 4; r++) {
                const int d = dq * 32 + ai * 16 + rq * 4 + r;
                outp[d * 64 + e] = acc[ai][bi][r];
            }
        }
}

// ---------------- kv reduce + Weff = blockdiag(kv) @ Wo^T ----------------
// Per (b,h): reduce 8 partials -> kv[d][e] bf16 in LDS, then
// Weff_b[o][h*64+d] = sum_e Wo[o][h*64+e] * kv[d][e].
__global__ __launch_bounds__(256) void kv_weff(
    const float* __restrict__ partial, const unsigned short* __restrict__ wob,
    unsigned short* __restrict__ weff)
{
    const int bh = blockIdx.x;           // 128 = b*16+h
    const int b = bh >> 4, h = bh & 15;

    __shared__ unsigned short kvs[64][72];
    __shared__ __align__(128) unsigned short Awo[128 * 64];

    const int tid  = threadIdx.x;        // 256, 4 waves
    const int lane = tid & 63;
    const int w    = tid >> 6;
    const int ml = lane & 15, kq = lane >> 4;

    // 1) reduce partials -> kvs (bf16)
    {
        float a[16];
        #pragma unroll
        for (int c = 0; c < 16; c++) a[c] = 0.f;
        #pragma unroll
        for (int p = 0; p < 8; p++) {
            const float* src = partial + ((size_t)bh * 8 + p) * 4096;
            #pragma unroll
            for (int c = 0; c < 16; c++) a[c] += src[c * 256 + tid];
        }
        #pragma unroll
        for (int c = 0; c < 16; c++) {
            const int idx = c * 256 + tid;       // d*64+e
            kvs[idx >> 6][idx & 63] = f2bf(a[c]);
        }
    }
    __syncthreads();

    // hoisted B fragments: B[n=d][k=e]
    bf16x8 bfv[4][2];
    #pragma unroll
    for (int nj = 0; nj < 4; nj++)
        #pragma unroll
        for (int ks = 0; ks < 2; ks++)
            bfv[nj][ks] = *(const bf16x8*)&kvs[nj * 16 + ml][ks * 32 + kq * 8];

    // staging offsets (inverse-swizzled source), 256 threads x 4 x 16B = 16KB
    int voff[4];
    #pragma unroll
    for (int u = 0; u < 4; u++) {
        const int p  = (u * 256 + tid) * 16;
        const int qq = p ^ (((p >> 7) & 7) << 4);
        voff[u] = (qq >> 7) * 2048 + (qq & 127);
    }
    const int wb = tid & ~63;
    const char* gsrc = (const char*)wob + (size_t)h * 128;  // Wo[.][h*64..]
    unsigned short* dstb = weff + (size_t)b * 1024 * 1024 + h * 64;
    const int rq = lane >> 4, cl = lane & 15;

    for (int oc = 0; oc < 8; ++oc) {
        __syncthreads();                 // prev chunk's Awo reads complete
        #pragma unroll
        for (int u = 0; u < 4; u++)
            gload_lds16(gsrc + (size_t)oc * 128 * 2048 + voff[u],
                        (char*)Awo + (size_t)(u * 256 + wb) * 16);
        asm volatile("s_waitcnt vmcnt(0)" ::: "memory");
        __syncthreads();

        bf16x8 af[2][2];
        #pragma unroll
        for (int mi = 0; mi < 2; mi++) {
            const int r128 = w * 32 + mi * 16 + ml;
            const int sw = (r128 & 7) << 4;
            #pragma unroll
            for (int ks = 0; ks < 2; ks++)
                af[mi][ks] = *(const bf16x8*)((const char*)Awo +
                    (((r128 * 128) + ks * 64 + kq * 16) ^ sw));
        }

        f32x4 acc[2][4];
        f32x4 zero4 = {0.f, 0.f, 0.f, 0.f};
        #pragma unroll
        for (int mi = 0; mi < 2; mi++)
            #pragma unroll
            for (int nj = 0; nj < 4; nj++) acc[mi][nj] = zero4;

        #pragma unroll
        for (int ks = 0; ks < 2; ks++)
            #pragma unroll
            for (int mi = 0; mi < 2; mi++)
                #pragma unroll
                for (int nj = 0; nj < 4; nj++)
                    acc[mi][nj] = __builtin_amdgcn_mfma_f32_16x16x32_bf16(
                        af[mi][ks], bfv[nj][ks], acc[mi][nj], 0, 0, 0);

        #pragma unroll
        for (int mi = 0; mi < 2; mi++)
            #pragma unroll
            for (int nj = 0; nj < 4; nj++)
                #pragma unroll
                for (int r = 0; r < 4; r++) {
                    const int o = oc * 128 + w * 32 + mi * 16 + rq * 4 + r;
                    dstb[(size_t)o * 1024 + nj * 16 + cl] = f2bf(acc[mi][nj][r]);
                }
    }
}

extern "C" void kernel_launch(void* const* d_in, const int* in_sizes, int n_in,
                              void* d_out, int out_size, void* d_ws, size_t ws_size,
                              hipStream_t stream) {
    const float* x  = (const float*)d_in[0];
    const float* Wq = (const float*)d_in[1];
    const float* bq = (const float*)d_in[2];
    const float* Wk = (const float*)d_in[3];
    const float* Wv = (const float*)d_in[4];
    const float* bv = (const float*)d_in[5];
    const float* Wo = (const float*)d_in[6];
    const float* bo = (const float*)d_in[7];
    float* out = (float*)d_out;

    const int B = 8, T = 4096, D = 1024;
    const int M = B * T;                       // 32768
    const float scale = 0.35355339059327379f;  // 64^-0.25
    const size_t MD = (size_t)M * D;
    const size_t WN = (size_t)D * D;

    unsigned short* xb    = (unsigned short*)d_ws;
    unsigned short* wqb   = xb + MD;           // wq,wk,wv contiguous = [3072][1024]
    unsigned short* wkb   = wqb + WN;
    unsigned short* wvb   = wkb + WN;
    unsigned short* wob   = wvb + WN;
    unsigned short* phiq  = wob + WN;
    unsigned short* phik  = phiq + MD;
    unsigned short* vb    = phik + MD;
    unsigned short* weff  = vb + MD;                    // [8][1024][1024] bf16 = 16 MB
    float*          part  = (float*)(weff + (size_t)8 * 1024 * 1024); // 16 MB
    (void)ws_size; (void)in_sizes; (void)n_in; (void)out_size;

    dim3 blk(256);

    // 1) cast x + weights to bf16 (grid-stride, 2048 blocks)
    cast_all<<<dim3(2048), blk, 0, stream>>>(
        x, xb, Wq, wqb, Wk, wkb, Wv, wvb, Wo, wob, MD, WN);

    // 2) fused q/k/v projection: one GEMM M=32768, N=3072, K=1024
    qkv_gemm256<<<dim3(1536), dim3(512), 0, stream>>>(
        xb, wqb, bq, bv, phiq, phik, vb, scale);

    // 3) kv partials, then reduce + fold Wo into per-batch Weff
    kv_part<<<dim3(8, 128), blk, 0, stream>>>(phik, vb, part, T, D);
    kv_weff<<<dim3(128), blk, 0, stream>>>(part, wob, weff);

    // 4) final projection directly from phiq: out = phiq @ Weff_b^T + bo
    out_gemm256<<<dim3(512), dim3(512), 0, stream>>>(phiq, weff, bo, out);
}

// Round 9
// 582.644 us; speedup vs baseline: 1.4893x; 1.0190x over previous
//
#include <hip/hip_runtime.h>
#include <math.h>

typedef short bf16x8 __attribute__((ext_vector_type(8)));
typedef float f32x4  __attribute__((ext_vector_type(4)));

__device__ __forceinline__ float phi_act(float t) {
    return t / (1.0f + __expf(-t)) + 1.0f;   // silu(t)+1
}

__device__ __forceinline__ unsigned short f2bf(float f) {
    union { float f; unsigned int u; } un; un.f = f;
    unsigned int r = un.u + 0x7fffu + ((un.u >> 16) & 1u);  // RNE
    return (unsigned short)(r >> 16);
}

__device__ __forceinline__ void gload_lds16(const void* g, void* l) {
    __builtin_amdgcn_global_load_lds(
        (const __attribute__((address_space(1))) void*)g,
        (__attribute__((address_space(3))) void*)l, 16, 0, 0);
}

// ============================================================================
// GEMM body: R3/R5/R6 verified structure (qkv 236us, MfmaUtil 38%) -- FROZEN.
// R8 A/B evidence: s_setprio(1) around MFMA = +4% on this schedule (KEEP).
// 24 ds_read_b128 per wave per K-tile, 3 gated phases + 1 free phase,
// counted vmcnt FIFO, LDS XOR-swizzle via inverse-swizzled global source.
// vmcnt FIFO ledger (stage issue order per tile = [a0',b0',b1',a1']):
//   P0 entry: outstanding = [a0,b0,b1,a1](8) -> vmcnt(4) completes a0,b0
//   P1 entry: [b1,a1,a0',b0'](8)            -> vmcnt(6) completes b1
//   P2 entry: [a1,a0',b0',b1'](8)           -> vmcnt(6) completes a1
//   (t=15: no new stages -> gates 4/2/0)
// WAR: stage in phase p targets a slot whose last read drained at that wave's
// lgkm(0) in the same phase of tile t-1 -> safe.
// NOTE (R7 lesson): per-block __threadfence (device scope) costs ~300us at
// 1024 blocks on MI355X (L2 wb/inv storm) -- never fuse via fences here.
// ============================================================================

__device__ __forceinline__ void stage2(const char* g, int voff0, int voff1,
                                       char* l, int wb16) {
    gload_lds16(g + voff0, l + wb16);
    gload_lds16(g + voff1, l + 8192 + wb16);
}

#define LOAD_AF(buf, ah) do {                                                   \
    const char* _s = (const char*)&As[buf][ah][0];                              \
    _Pragma("unroll")                                                           \
    for (int _mi = 0; _mi < 4; _mi++) {                                         \
        const int _row = qm * 64 + _mi * 16 + ml;                               \
        const int _sw = (_row & 7) << 4;                                        \
        _Pragma("unroll")                                                       \
        for (int _ks = 0; _ks < 2; _ks++)                                       \
            af[_mi][_ks] = *(const bf16x8*)(_s +                                \
                (((_row * 128) + _ks * 64 + kq * 16) ^ _sw));                   \
    }                                                                           \
} while (0)

#define LOAD_BF_TO(dst, buf, bh) do {                                           \
    const char* _s = (const char*)&Bs[buf][bh][0];                              \
    _Pragma("unroll")                                                           \
    for (int _nj = 0; _nj < 2; _nj++) {                                         \
        const int _col = qn * 32 + _nj * 16 + ml;                               \
        const int _sw = (_col & 7) << 4;                                        \
        _Pragma("unroll")                                                       \
        for (int _ks = 0; _ks < 2; _ks++)                                       \
            dst[_nj][_ks] = *(const bf16x8*)(_s +                               \
                (((_col * 128) + _ks * 64 + kq * 16) ^ _sw));                   \
    }                                                                           \
} while (0)

#define MFMA_Q(Q, B) do {                                                       \
    __builtin_amdgcn_s_setprio(1);                                              \
    _Pragma("unroll")                                                           \
    for (int _mi = 0; _mi < 4; _mi++)                                           \
        _Pragma("unroll")                                                       \
        for (int _nj = 0; _nj < 2; _nj++)                                       \
            _Pragma("unroll")                                                   \
            for (int _ks = 0; _ks < 2; _ks++)                                   \
                acc[Q][_mi][_nj] = __builtin_amdgcn_mfma_f32_16x16x32_bf16(     \
                    af[_mi][_ks], B[_nj][_ks], acc[Q][_mi][_nj], 0, 0, 0);      \
    __builtin_amdgcn_s_setprio(0);                                              \
} while (0)

// KIND 0: fused QKV (W = concat[Wq;Wk;Wv], N=3072, per-column-block epilogue)
// KIND 1: out projection, B = per-batch Weff_b (fp32 store + bias, N=1024)
template<int KIND>
__device__ __forceinline__ void gemm256_body(
    const unsigned short* __restrict__ A, const unsigned short* __restrict__ W,
    const float* __restrict__ bq, const float* __restrict__ bv,
    unsigned short* __restrict__ oq, unsigned short* __restrict__ okk,
    unsigned short* __restrict__ ov, float* __restrict__ outF,
    const float* __restrict__ bo, float scale, int NBN)
{
    __shared__ __align__(128) unsigned short As[2][2][128 * 64];
    __shared__ __align__(128) unsigned short Bs[2][2][128 * 64];

    const int tid  = threadIdx.x;
    const int lane = tid & 63;
    const int w    = tid >> 6;
    const int qm   = w >> 2;         // 0..1 : 64-row band within quadrant
    const int qn   = w & 3;          // 0..3 : 32-col band within quadrant
    const int ml   = lane & 15;
    const int kq   = lane >> 4;

    // T1: bijective XCD swizzle (nwg % 8 == 0), bm-major chunks
    const int nwg  = (int)gridDim.x;
    const int bid  = (int)blockIdx.x;
    const int sbid = (bid & 7) * (nwg >> 3) + (bid >> 3);
    const int bn   = sbid % NBN;
    const int bm   = sbid / NBN;

    const char* pA = (const char*)(A + (size_t)bm * 256 * 1024);
    const unsigned short* Wbase =
        (KIND == 1) ? (W + (size_t)(bm >> 4) * 1024 * 1024) : W;
    const char* pB = (const char*)(Wbase + (size_t)bn * 256 * 1024);

    // per-lane staging offsets (inverse-swizzled global source), computed once
    int voff[2];
    #pragma unroll
    for (int u = 0; u < 2; u++) {
        const int p  = (u * 512 + tid) * 16;
        const int qq = p ^ (((p >> 7) & 7) << 4);
        voff[u] = (qq >> 7) * 2048 + (qq & 127);
    }
    const int wb16 = (tid & ~63) * 16;

    f32x4 acc[4][4][2];
    f32x4 zero4 = {0.f, 0.f, 0.f, 0.f};
    #pragma unroll
    for (int q = 0; q < 4; q++)
        #pragma unroll
        for (int mi = 0; mi < 4; mi++)
            #pragma unroll
            for (int nj = 0; nj < 2; nj++) acc[q][mi][nj] = zero4;

    bf16x8 af[4][2], bf0[2][2], bf1[2][2];

    // Prologue: stage tile0 in steady-state FIFO order [a0, b0, b1, a1]
    stage2(pA,              voff[0], voff[1], (char*)&As[0][0][0], wb16);
    stage2(pB,              voff[0], voff[1], (char*)&Bs[0][0][0], wb16);
    stage2(pB + 256 * 1024, voff[0], voff[1], (char*)&Bs[0][1][0], wb16);
    stage2(pA + 256 * 1024, voff[0], voff[1], (char*)&As[0][1][0], wb16);

    for (int t = 0; t < 16; ++t) {
        const int buf = t & 1;
        const char* A0n = pA + (size_t)(t + 1) * 128;            // next K-tile
        const char* A1n = A0n + 256 * 1024;
        const char* B0n = pB + (size_t)(t + 1) * 128;
        const char* B1n = B0n + 256 * 1024;
        const bool st = (t + 1 < 16);

        // ---------------- P0 : Q0 = af0 x bf0 ----------------
        asm volatile("s_waitcnt vmcnt(4)" ::: "memory");
        __builtin_amdgcn_s_barrier();
        asm volatile("" ::: "memory");
        LOAD_AF(buf, 0);
        LOAD_BF_TO(bf0, buf, 0);
        if (st) {
            stage2(A0n, voff[0], voff[1], (char*)&As[buf ^ 1][0][0], wb16);
            stage2(B0n, voff[0], voff[1], (char*)&Bs[buf ^ 1][0][0], wb16);
        }
        asm volatile("s_waitcnt lgkmcnt(0)" ::: "memory");
        MFMA_Q(0, bf0);

        // ---------------- P1 : Q1 = af0 x bf1 ----------------
        if (st) { asm volatile("s_waitcnt vmcnt(6)" ::: "memory"); }
        else    { asm volatile("s_waitcnt vmcnt(2)" ::: "memory"); }
        __builtin_amdgcn_s_barrier();
        asm volatile("" ::: "memory");
        LOAD_BF_TO(bf1, buf, 1);
        if (st) stage2(B1n, voff[0], voff[1], (char*)&Bs[buf ^ 1][1][0], wb16);
        asm volatile("s_waitcnt lgkmcnt(0)" ::: "memory");
        MFMA_Q(1, bf1);

        // ---------------- P2 : Q2 = af1 x bf1 ----------------
        if (st) { asm volatile("s_waitcnt vmcnt(6)" ::: "memory"); }
        else    { asm volatile("s_waitcnt vmcnt(0)" ::: "memory"); }
        __builtin_amdgcn_s_barrier();
        asm volatile("" ::: "memory");
        LOAD_AF(buf, 1);
        if (st) stage2(A1n, voff[0], voff[1], (char*)&As[buf ^ 1][1][0], wb16);
        asm volatile("s_waitcnt lgkmcnt(0)" ::: "memory");
        MFMA_Q(2, bf1);

        // ---------------- P3 : Q3 = af1 x bf0 (no sync) ----------------
        MFMA_Q(3, bf0);
    }

    // Epilogue
    const int rq = lane >> 4, cl = lane & 15;
    #pragma unroll
    for (int q = 0; q < 4; q++) {
        const int qr = (q >> 1) * 128;
        const int qc = ((q == 1) || (q == 2)) ? 128 : 0;
        #pragma unroll
        for (int nj = 0; nj < 2; nj++) {
            const int colg = bn * 256 + qc + qn * 32 + nj * 16 + cl;
            if constexpr (KIND == 0) {
                const int z    = colg >> 10;        // uniform across the 16 lanes
                const int lcol = colg & 1023;
                const float bias = (z == 0) ? bq[lcol] : ((z == 2) ? bv[lcol] : 0.f);
                unsigned short* dst = (z == 0) ? oq : ((z == 1) ? okk : ov);
                #pragma unroll
                for (int mi = 0; mi < 4; mi++) {
                    const int row0 = bm * 256 + qr + qm * 64 + mi * 16 + rq * 4;
                    #pragma unroll
                    for (int r = 0; r < 4; r++) {
                        float vv = acc[q][mi][nj][r] + bias;
                        if (z < 2) vv = phi_act(vv * scale);
                        dst[(size_t)(row0 + r) * 1024 + lcol] = f2bf(vv);
                    }
                }
            } else {
                const float bias = bo[colg];
                #pragma unroll
                for (int mi = 0; mi < 4; mi++) {
                    const int row0 = bm * 256 + qr + qm * 64 + mi * 16 + rq * 4;
                    #pragma unroll
                    for (int r = 0; r < 4; r++)
                        outF[(size_t)(row0 + r) * 1024 + colg] = acc[q][mi][nj][r] + bias;
                }
            }
        }
    }
}

__global__ __launch_bounds__(512, 2) void qkv_gemm256(
    const unsigned short* __restrict__ xb,
    const unsigned short* __restrict__ wcat,   // wq,wk,wv contiguous [3072][1024]
    const float* __restrict__ bq, const float* __restrict__ bv,
    unsigned short* __restrict__ phiq, unsigned short* __restrict__ phik,
    unsigned short* __restrict__ vb, float scale)
{
    gemm256_body<0>(xb, wcat, bq, bv, phiq, phik, vb, nullptr, nullptr, scale, 12);
}

__global__ __launch_bounds__(512, 2) void out_gemm256(
    const unsigned short* __restrict__ A, const unsigned short* __restrict__ W,
    const float* __restrict__ bo, float* __restrict__ out)
{
    gemm256_body<1>(A, W, nullptr, nullptr, nullptr, nullptr, nullptr, out, bo, 1.0f, 4);
}

// ---------------- cast ----------------
__global__ __launch_bounds__(256) void cast_all(
    const float* __restrict__ x,  unsigned short* __restrict__ xb,
    const float* __restrict__ w0, unsigned short* __restrict__ w0b,
    const float* __restrict__ w1, unsigned short* __restrict__ w1b,
    const float* __restrict__ w2, unsigned short* __restrict__ w2b,
    const float* __restrict__ w3, unsigned short* __restrict__ w3b,
    size_t nx, size_t nw)
{
    size_t i = ((size_t)blockIdx.x * 256 + threadIdx.x) * 4;
    const float* s; unsigned short* d; size_t off;
    if (i < nx)               { s = x;  d = xb;  off = i; }
    else if (i < nx + nw)     { s = w0; d = w0b; off = i - nx; }
    else if (i < nx + 2 * nw) { s = w1; d = w1b; off = i - nx - nw; }
    else if (i < nx + 3 * nw) { s = w2; d = w2b; off = i - nx - 2 * nw; }
    else                      { s = w3; d = w3b; off = i - nx - 3 * nw; }
    float4 v = *(const float4*)(s + off);
    ushort4 o;
    o.x = f2bf(v.x); o.y = f2bf(v.y); o.z = f2bf(v.z); o.w = f2bf(v.w);
    *(ushort4*)(d + off) = o;
}

// ---------------- kv = phi_k^T v : MFMA split-T partials ----------------
// Packed ds_write_b32 transpose (2 t-rows/thread), t-octet XOR swizzle:
// stored col for (d,t) is t ^ ((d>>3)<<3). Bank audit: 2 lanes/bank = free.
__global__ __launch_bounds__(256) void kv_part(
    const unsigned short* __restrict__ phiK, const unsigned short* __restrict__ V,
    float* __restrict__ partial, int Ttot, int D)
{
    const int tc = blockIdx.x, bh = blockIdx.y;
    const int b = bh >> 4, h = bh & 15;
    const int tbase = tc * 512;

    __shared__ unsigned short pkT[64][72];   // [d][t-swizzled], +8 pad
    __shared__ unsigned short vvT[64][72];   // [e][t-swizzled]

    const int tid  = threadIdx.x;
    const int lane = tid & 63;
    const int w    = tid >> 6;
    const int dq = w >> 1, eq = w & 1;
    const int kq = lane >> 4, ml = lane & 15;

    const int tq  = tid >> 3;            // 0..31 (t-pair index)
    const int oct = tid & 7;             // d-octet
    const int d8  = oct * 8;
    const int tw0 = (tq * 2) ^ (oct << 3);  // swizzled column (even)

    f32x4 zero4 = {0.f, 0.f, 0.f, 0.f};
    f32x4 acc[2][2];
    acc[0][0] = zero4; acc[0][1] = zero4; acc[1][0] = zero4; acc[1][1] = zero4;

    const size_t base = (size_t)b * Ttot * D + h * 64;

#define PACKW(arr, lo, hi, i0)                                                   \
    *(unsigned int*)&arr[d8 + i0    ][tw0] = ((lo) & 0xffffu) | ((hi) << 16);    \
    *(unsigned int*)&arr[d8 + i0 + 1][tw0] = ((lo) >> 16) | ((hi) & 0xffff0000u);

    for (int c8 = 0; c8 < 8; c8++) {
        const int t0 = tbase + c8 * 64;
        __syncthreads();
        {
            const size_t g0 = base + (size_t)(t0 + tq * 2) * D + d8;
            uint4 k0 = *(const uint4*)(phiK + g0);
            uint4 k1 = *(const uint4*)(phiK + g0 + D);
            uint4 v0 = *(const uint4*)(V + g0);
            uint4 v1 = *(const uint4*)(V + g0 + D);
            PACKW(pkT, k0.x, k1.x, 0) PACKW(pkT, k0.y, k1.y, 2)
            PACKW(pkT, k0.z, k1.z, 4) PACKW(pkT, k0.w, k1.w, 6)
            PACKW(vvT, v0.x, v1.x, 0) PACKW(vvT, v0.y, v1.y, 2)
            PACKW(vvT, v0.z, v1.z, 4) PACKW(vvT, v0.w, v1.w, 6)
        }
        __syncthreads();

        #pragma unroll
        for (int ks = 0; ks < 2; ks++) {
            bf16x8 afr[2], bfv[2];
            #pragma unroll
            for (int ai = 0; ai < 2; ai++) {
                const int row = dq * 32 + ai * 16 + ml;
                const int col = ((ks * 4 + kq) ^ ((row >> 3) & 7)) << 3;
                afr[ai] = *(const bf16x8*)&pkT[row][col];
            }
            #pragma unroll
            for (int bi = 0; bi < 2; bi++) {
                const int row = eq * 32 + bi * 16 + ml;
                const int col = ((ks * 4 + kq) ^ ((row >> 3) & 7)) << 3;
                bfv[bi] = *(const bf16x8*)&vvT[row][col];
            }
            #pragma unroll
            for (int ai = 0; ai < 2; ai++)
                #pragma unroll
                for (int bi = 0; bi < 2; bi++)
                    acc[ai][bi] = __builtin_amdgcn_mfma_f32_16x16x32_bf16(
                        afr[ai], bfv[bi], acc[ai][bi], 0, 0, 0);
        }
    }
#undef PACKW

    float* outp = partial + ((size_t)bh * 8 + tc) * 4096;
    const int rq = lane >> 4, cl = lane & 15;
    #pragma unroll
    for (int ai = 0; ai < 2; ai++)
        #pragma unroll
        for (int bi = 0; bi < 2; bi++) {
            const int e = eq * 32 + bi * 16 + cl;
            #pragma unroll
            for (int r = 0; r < 4; r++) {
                const int d = dq * 32 + ai * 16 + rq * 4 + r;
                outp[d * 64 + e] = acc[ai][bi][r];
            }
        }
}

// ---------------- kv reduce + Weff = blockdiag(kv) @ Wo^T ----------------
// Per (b,h): reduce 8 partials -> kv[d][e] bf16 in LDS, then
// Weff_b[o][h*64+d] = sum_e Wo[o][h*64+e] * kv[d][e].
__global__ __launch_bounds__(256) void kv_weff(
    const float* __restrict__ partial, const unsigned short* __restrict__ wob,
    unsigned short* __restrict__ weff)
{
    const int bh = blockIdx.x;           // 128 = b*16+h
    const int b = bh >> 4, h = bh & 15;

    __shared__ unsigned short kvs[64][72];
    __shared__ __align__(128) unsigned short Awo[128 * 64];

    const int tid  = threadIdx.x;        // 256, 4 waves
    const int lane = tid & 63;
    const int w    = tid >> 6;
    const int ml = lane & 15, kq = lane >> 4;

    // 1) reduce partials -> kvs (bf16)
    {
        float a[16];
        #pragma unroll
        for (int c = 0; c < 16; c++) a[c] = 0.f;
        #pragma unroll
        for (int p = 0; p < 8; p++) {
            const float* src = partial + ((size_t)bh * 8 + p) * 4096;
            #pragma unroll
            for (int c = 0; c < 16; c++) a[c] += src[c * 256 + tid];
        }
        #pragma unroll
        for (int c = 0; c < 16; c++) {
            const int idx = c * 256 + tid;       // d*64+e
            kvs[idx >> 6][idx & 63] = f2bf(a[c]);
        }
    }
    __syncthreads();

    // hoisted B fragments: B[n=d][k=e]
    bf16x8 bfv[4][2];
    #pragma unroll
    for (int nj = 0; nj < 4; nj++)
        #pragma unroll
        for (int ks = 0; ks < 2; ks++)
            bfv[nj][ks] = *(const bf16x8*)&kvs[nj * 16 + ml][ks * 32 + kq * 8];

    // staging offsets (inverse-swizzled source), 256 threads x 4 x 16B = 16KB
    int voff[4];
    #pragma unroll
    for (int u = 0; u < 4; u++) {
        const int p  = (u * 256 + tid) * 16;
        const int qq = p ^ (((p >> 7) & 7) << 4);
        voff[u] = (qq >> 7) * 2048 + (qq & 127);
    }
    const int wb = tid & ~63;
    const char* gsrc = (const char*)wob + (size_t)h * 128;  // Wo[.][h*64..]
    unsigned short* dstb = weff + (size_t)b * 1024 * 1024 + h * 64;
    const int rq = lane >> 4, cl = lane & 15;

    for (int oc = 0; oc < 8; ++oc) {
        __syncthreads();                 // prev chunk's Awo reads complete
        #pragma unroll
        for (int u = 0; u < 4; u++)
            gload_lds16(gsrc + (size_t)oc * 128 * 2048 + voff[u],
                        (char*)Awo + (size_t)(u * 256 + wb) * 16);
        asm volatile("s_waitcnt vmcnt(0)" ::: "memory");
        __syncthreads();

        bf16x8 af[2][2];
        #pragma unroll
        for (int mi = 0; mi < 2; mi++) {
            const int r128 = w * 32 + mi * 16 + ml;
            const int sw = (r128 & 7) << 4;
            #pragma unroll
            for (int ks = 0; ks < 2; ks++)
                af[mi][ks] = *(const bf16x8*)((const char*)Awo +
                    (((r128 * 128) + ks * 64 + kq * 16) ^ sw));
        }

        f32x4 acc[2][4];
        f32x4 zero4 = {0.f, 0.f, 0.f, 0.f};
        #pragma unroll
        for (int mi = 0; mi < 2; mi++)
            #pragma unroll
            for (int nj = 0; nj < 4; nj++) acc[mi][nj] = zero4;

        #pragma unroll
        for (int ks = 0; ks < 2; ks++)
            #pragma unroll
            for (int mi = 0; mi < 2; mi++)
                #pragma unroll
                for (int nj = 0; nj < 4; nj++)
                    acc[mi][nj] = __builtin_amdgcn_mfma_f32_16x16x32_bf16(
                        af[mi][ks], bfv[nj][ks], acc[mi][nj], 0, 0, 0);

        #pragma unroll
        for (int mi = 0; mi < 2; mi++)
            #pragma unroll
            for (int nj = 0; nj < 4; nj++)
                #pragma unroll
                for (int r = 0; r < 4; r++) {
                    const int o = oc * 128 + w * 32 + mi * 16 + rq * 4 + r;
                    dstb[(size_t)o * 1024 + nj * 16 + cl] = f2bf(acc[mi][nj][r]);
                }
    }
}

extern "C" void kernel_launch(void* const* d_in, const int* in_sizes, int n_in,
                              void* d_out, int out_size, void* d_ws, size_t ws_size,
                              hipStream_t stream) {
    const float* x  = (const float*)d_in[0];
    const float* Wq = (const float*)d_in[1];
    const float* bq = (const float*)d_in[2];
    const float* Wk = (const float*)d_in[3];
    const float* Wv = (const float*)d_in[4];
    const float* bv = (const float*)d_in[5];
    const float* Wo = (const float*)d_in[6];
    const float* bo = (const float*)d_in[7];
    float* out = (float*)d_out;

    const int B = 8, T = 4096, D = 1024;
    const int M = B * T;                       // 32768
    const float scale = 0.35355339059327379f;  // 64^-0.25
    const size_t MD = (size_t)M * D;
    const size_t WN = (size_t)D * D;

    unsigned short* xb    = (unsigned short*)d_ws;
    unsigned short* wqb   = xb + MD;           // wq,wk,wv contiguous = [3072][1024]
    unsigned short* wkb   = wqb + WN;
    unsigned short* wvb   = wkb + WN;
    unsigned short* wob   = wvb + WN;
    unsigned short* phiq  = wob + WN;
    unsigned short* phik  = phiq + MD;
    unsigned short* vb    = phik + MD;
    unsigned short* weff  = vb + MD;                    // [8][1024][1024] bf16 = 16 MB
    float*          part  = (float*)(weff + (size_t)8 * 1024 * 1024); // 16 MB
    (void)ws_size; (void)in_sizes; (void)n_in; (void)out_size;

    dim3 blk(256);

    // 1) cast x + weights to bf16
    {
        size_t total4 = (MD + 4 * WN) / 4;
        cast_all<<<dim3((unsigned)(total4 / 256)), blk, 0, stream>>>(
            x, xb, Wq, wqb, Wk, wkb, Wv, wvb, Wo, wob, MD, WN);
    }

    // 2) fused q/k/v projection: one GEMM M=32768, N=3072, K=1024
    qkv_gemm256<<<dim3(1536), dim3(512), 0, stream>>>(
        xb, wqb, bq, bv, phiq, phik, vb, scale);

    // 3) kv partials, then reduce + fold Wo into per-batch Weff
    kv_part<<<dim3(8, 128), blk, 0, stream>>>(phik, vb, part, T, D);
    kv_weff<<<dim3(128), blk, 0, stream>>>(part, wob, weff);

    // 4) final projection directly from phiq: out = phiq @ Weff_b^T + bo
    out_gemm256<<<dim3(512), dim3(512), 0, stream>>>(phiq, weff, bo, out);
}